// Round 17
// baseline (251.973 us; speedup 1.0000x reference)
//
#include <hip/hip_runtime.h>

#define D 64
#define K 1024
#define NTOK (32 * 4096)        // 131072 tokens
#define Q_ELEMS ((size_t)NTOK * D)
#define OH_ELEMS ((size_t)NTOK * K)

typedef short bf16x8 __attribute__((ext_vector_type(8)));
typedef float f32x4 __attribute__((ext_vector_type(4)));

// ws layout (bytes): e2[1024] f32 | etf[K][D] f32 | ethF frags | etlF frags
#define WS_ETF_OFF 4096                          // 256 KB exact transposed E
#define WS_ETH_OFF (4096 + 262144)               // 128 KB bf16-hi fragments
#define WS_ETL_OFF (4096 + 262144 + 131072)      // 128 KB bf16-lo fragments
#define WS_NEED    (4096 + 262144 + 131072 + 131072)

__device__ __forceinline__ unsigned short f2bf(float f) {   // RNE f32->bf16
    unsigned u = __float_as_uint(f);
    unsigned r = u + 0x7FFFu + ((u >> 16) & 1u);
    return (unsigned short)(r >> 16);
}
__device__ __forceinline__ float bf2f(unsigned short h) {
    return __uint_as_float(((unsigned)h) << 16);
}

// ---- prep: e2 (exact, d-ascending chain), etf, FRAGMENT-ORDERED bf16 tables ----
__global__ void prep_kernel(const float* __restrict__ E, float* __restrict__ ws) {
    int k = blockIdx.x * 256 + threadIdx.x;      // code
    float* e2 = ws;
    float* etf = (float*)((char*)ws + WS_ETF_OFF);
    unsigned short* ethF = (unsigned short*)((char*)ws + WS_ETH_OFF);
    unsigned short* etlF = (unsigned short*)((char*)ws + WS_ETL_OFF);

    const int tile = k >> 6, ct = (k >> 4) & 3, l15 = k & 15;
    float s = 0.f;
    #pragma unroll
    for (int d = 0; d < D; ++d) {
        float v = E[d * K + k];
        s = fmaf(v, v, s);
        etf[k * D + d] = v;
        unsigned short h = f2bf(v);
        unsigned short l = f2bf(v - bf2f(h));
        const int ks = d >> 5, g = (d >> 3) & 3, j = d & 7;
        const int slot = (((tile * 4 + ct) * 2 + ks) * 64 + g * 16 + l15) * 8 + j;
        ethF[slot] = h;
        etlF[slot] = l;
    }
    e2[k] = s;
}

// ---- exact rescore (bit-identical R1 chain, canonical ascending K); lane 0..63 ----
__device__ __attribute__((noinline)) int rescore_token(
    const float* __restrict__ X, const float* __restrict__ E,
    const float* __restrict__ e2g, int tok, int lane)
{
    const float* xr = X + (size_t)tok * D;
    float bestv = 3.4e38f; int besti = 0;
    #pragma unroll 1
    for (int sb = 0; sb < 2; ++sb) {
        const int k0 = lane * 16 + sb * 8;
        float dot[8] = {0.f,0.f,0.f,0.f,0.f,0.f,0.f,0.f};
        #pragma unroll 1
        for (int db = 0; db < 4; ++db) {
            float4 xc0 = *reinterpret_cast<const float4*>(xr + db * 16 + 0);
            float4 xc1 = *reinterpret_cast<const float4*>(xr + db * 16 + 4);
            float4 xc2 = *reinterpret_cast<const float4*>(xr + db * 16 + 8);
            float4 xc3 = *reinterpret_cast<const float4*>(xr + db * 16 + 12);
            float xs[16] = {xc0.x,xc0.y,xc0.z,xc0.w, xc1.x,xc1.y,xc1.z,xc1.w,
                            xc2.x,xc2.y,xc2.z,xc2.w, xc3.x,xc3.y,xc3.z,xc3.w};
            #pragma unroll
            for (int dd = 0; dd < 16; ++dd) {           // d ascending
                const int d = db * 16 + dd;
                float4 e0 = *reinterpret_cast<const float4*>(E + (size_t)d * K + k0);
                float4 e1 = *reinterpret_cast<const float4*>(E + (size_t)d * K + k0 + 4);
                dot[0] = fmaf(xs[dd], e0.x, dot[0]); dot[1] = fmaf(xs[dd], e0.y, dot[1]);
                dot[2] = fmaf(xs[dd], e0.z, dot[2]); dot[3] = fmaf(xs[dd], e0.w, dot[3]);
                dot[4] = fmaf(xs[dd], e1.x, dot[4]); dot[5] = fmaf(xs[dd], e1.y, dot[5]);
                dot[6] = fmaf(xs[dd], e1.z, dot[6]); dot[7] = fmaf(xs[dd], e1.w, dot[7]);
            }
        }
        float4 ez0 = *reinterpret_cast<const float4*>(e2g + k0);
        float4 ez1 = *reinterpret_cast<const float4*>(e2g + k0 + 4);
        float ezs[8] = {ez0.x,ez0.y,ez0.z,ez0.w, ez1.x,ez1.y,ez1.z,ez1.w};
        #pragma unroll
        for (int j = 0; j < 8; ++j) {
            float dist = fmaf(-2.f, dot[j], ezs[j]);
            if (dist < bestv) { bestv = dist; besti = k0 + j; }
        }
    }
    #pragma unroll
    for (int mm = 1; mm <= 32; mm <<= 1) {
        float ob = __shfl_xor(bestv, mm, 64);
        int   oi = __shfl_xor(besti, mm, 64);
        bool take = (ob < bestv) || (ob == bestv && oi < besti);
        bestv = take ? ob : bestv;
        besti = take ? oi : besti;
    }
    return besti;
}

// ---- main: 512 threads = 4 compute waves (distance, NO global stores) +
//      4 writer waves (one-hot zero stream + all output stores).
//      Separate waves -> separate vmcnt: compute load-waits never drain stores.
__global__ __launch_bounds__(512, 4) void vq_fused_kernel(
    const float* __restrict__ X,
    const float* __restrict__ E,
    const float* __restrict__ ws_f,
    float* __restrict__ qout,
    float* __restrict__ oneh,
    float* __restrict__ idxout)
{
    // [buf][table][slot(ct*2+ks)][1KB]  = 32 KB staging + winner handoff
    __shared__ __align__(16) unsigned short btile[2][2][8][512];
    __shared__ int idxs[128];

    const int lane = threadIdx.x & 63;
    const int wave = threadIdx.x >> 6;            // 0..7 (wave-uniform branch)
    const size_t blkTok = (size_t)blockIdx.x * 128;

    const float* e2g = ws_f;
    const float* etf = (const float*)((const char*)ws_f + WS_ETF_OFF);
    const char* ethB = (const char*)ws_f + WS_ETH_OFF;
    const char* etlB = (const char*)ws_f + WS_ETL_OFF;

    if (wave < 4) {
        // ================= COMPUTE WAVES (R16 structure, no global stores) ====
        const int wv     = wave;
        const int lane15 = lane & 15;
        const int g      = lane >> 4;
        const int tokbase = (int)blkTok + wv * 32;

        bf16x8 ah[2][2], al[2][2];                // [mtile][ks], mapping proven R6-R16
        #pragma unroll
        for (int mt = 0; mt < 2; ++mt) {
            const float* xr = X + (size_t)(tokbase + mt * 16 + lane15) * D + g * 8;
            #pragma unroll
            for (int ks = 0; ks < 2; ++ks) {
                float4 v0 = *reinterpret_cast<const float4*>(xr + ks * 32);
                float4 v1 = *reinterpret_cast<const float4*>(xr + ks * 32 + 4);
                float xv[8] = {v0.x,v0.y,v0.z,v0.w, v1.x,v1.y,v1.z,v1.w};
                #pragma unroll
                for (int j = 0; j < 8; ++j) {
                    unsigned short h = f2bf(xv[j]);
                    ah[mt][ks][j] = (short)h;
                    al[mt][ks][j] = (short)f2bf(xv[j] - bf2f(h));
                }
            }
        }

        float bb[2][4] = {{3.4e38f,3.4e38f,3.4e38f,3.4e38f},{3.4e38f,3.4e38f,3.4e38f,3.4e38f}};
        float b2[2][4] = {{3.4e38f,3.4e38f,3.4e38f,3.4e38f},{3.4e38f,3.4e38f,3.4e38f,3.4e38f}};
        int   bi[2][4] = {{0,0,0,0},{0,0,0,0}};

        #define GLOAD_TILE(T, B)                                                      \
            do {                                                                      \
                _Pragma("unroll")                                                     \
                for (int cc = 0; cc < 4; ++cc) {                                      \
                    const int c = wv * 4 + cc;                                        \
                    const char* src = ((c < 8) ? ethB : etlB)                         \
                                      + (size_t)(T) * 8192 + (size_t)(c & 7) * 1024   \
                                      + (size_t)lane * 16;                            \
                    __builtin_amdgcn_global_load_lds(                                 \
                        (const __attribute__((address_space(1))) void*)src,           \
                        (__attribute__((address_space(3))) void*)&btile[B][c >> 3][c & 7][0], \
                        16, 0, 0);                                                    \
                }                                                                     \
            } while (0)

        GLOAD_TILE(0, 0);

        #pragma unroll 1
        for (int tile = 0; tile < 16; ++tile) {                 // 16 barriers
            const int buf = tile & 1;
            __syncthreads();
            if (tile < 15) GLOAD_TILE(tile + 1, buf ^ 1);

            #pragma unroll
            for (int ct = 0; ct < 4; ++ct) {
                const int code = tile * 64 + ct * 16 + lane15;
                f32x4 acc0 = {0.f,0.f,0.f,0.f};
                f32x4 acc1 = {0.f,0.f,0.f,0.f};
                #pragma unroll
                for (int ks = 0; ks < 2; ++ks) {
                    const int slot = ct * 2 + ks;
                    bf16x8 bh = reinterpret_cast<const bf16x8*>(&btile[buf][0][slot][0])[lane];
                    bf16x8 bl = reinterpret_cast<const bf16x8*>(&btile[buf][1][slot][0])[lane];
                    acc0 = __builtin_amdgcn_mfma_f32_16x16x32_bf16(ah[0][ks], bh, acc0, 0, 0, 0);
                    acc0 = __builtin_amdgcn_mfma_f32_16x16x32_bf16(ah[0][ks], bl, acc0, 0, 0, 0);
                    acc0 = __builtin_amdgcn_mfma_f32_16x16x32_bf16(al[0][ks], bh, acc0, 0, 0, 0);
                    acc1 = __builtin_amdgcn_mfma_f32_16x16x32_bf16(ah[1][ks], bh, acc1, 0, 0, 0);
                    acc1 = __builtin_amdgcn_mfma_f32_16x16x32_bf16(ah[1][ks], bl, acc1, 0, 0, 0);
                    acc1 = __builtin_amdgcn_mfma_f32_16x16x32_bf16(al[1][ks], bh, acc1, 0, 0, 0);
                }
                const float e2v = e2g[code];
                #pragma unroll
                for (int r = 0; r < 4; ++r) {   // C/D: col=lane15=code, row=g*4+r
                    float d0 = fmaf(-2.f, acc0[r], e2v);
                    b2[0][r] = fminf(b2[0][r], fmaxf(bb[0][r], d0));
                    if (d0 < bb[0][r]) { bb[0][r] = d0; bi[0][r] = code; }
                    float d1 = fmaf(-2.f, acc1[r], e2v);
                    b2[1][r] = fminf(b2[1][r], fmaxf(bb[1][r], d1));
                    if (d1 < bb[1][r]) { bb[1][r] = d1; bi[1][r] = code; }
                }
            }
        }

        // reduce best/best2 over the 16 lanes sharing each token row
        #pragma unroll
        for (int m = 1; m <= 8; m <<= 1) {
            #pragma unroll
            for (int mt = 0; mt < 2; ++mt) {
                #pragma unroll
                for (int r = 0; r < 4; ++r) {
                    float ob = __shfl_xor(bb[mt][r], m, 64);
                    float o2 = __shfl_xor(b2[mt][r], m, 64);
                    int   oi = __shfl_xor(bi[mt][r], m, 64);
                    float nb2 = fminf(fminf(b2[mt][r], o2), fmaxf(bb[mt][r], ob));
                    bool take = (ob < bb[mt][r]) || (ob == bb[mt][r] && oi < bi[mt][r]);
                    bb[mt][r] = take ? ob : bb[mt][r];
                    bi[mt][r] = take ? oi : bi[mt][r];
                    b2[mt][r] = nb2;
                }
            }
        }

        // margin-guarded exact rescore (tau = 0.125, proven R6-R16)
        #pragma unroll
        for (int mt = 0; mt < 2; ++mt) {
            #pragma unroll
            for (int r = 0; r < 4; ++r) {
                bool flag = (b2[mt][r] - bb[mt][r]) < 0.125f;
                unsigned long long m = __ballot(flag);
                if (m) {
                    #pragma unroll
                    for (int gg = 0; gg < 4; ++gg) {
                        if ((m >> (gg * 16)) & 1ULL) {
                            int ei = rescore_token(X, E, e2g, tokbase + mt * 16 + gg * 4 + r, lane);
                            if (g == gg) bi[mt][r] = ei;
                        }
                    }
                }
            }
        }

        // hand winners to writer waves (lanes with lane15==0 own token mt*16+g*4+r)
        if (lane15 == 0) {
            #pragma unroll
            for (int mt = 0; mt < 2; ++mt)
                #pragma unroll
                for (int r = 0; r < 4; ++r)
                    idxs[wv * 32 + mt * 16 + g * 4 + r] = bi[mt][r];
        }
        __syncthreads();                                        // barrier 17
    } else {
        // ================= WRITER WAVES: zeros paced by the same barriers =====
        const int w = wave - 4;                   // 0..3, owns rows w*32..w*32+31
        f32x4* ohz = reinterpret_cast<f32x4*>(oneh + (blkTok + (size_t)w * 32) * K);
        const f32x4 zv = {0.f, 0.f, 0.f, 0.f};

        #pragma unroll 1
        for (int t = 0; t < 16; ++t) {                          // 16 barriers
            __syncthreads();
            #pragma unroll
            for (int zi = 0; zi < 8; ++zi)                      // 8 x 1KB nt chunks
                __builtin_nontemporal_store(zv, ohz + (t * 8 + zi) * 64 + lane);
        }
        __syncthreads();                                        // barrier 17:
        // each wave drained its own stores entering here -> all zeros complete,
        // and compute waves' idxs[] writes are visible.

        const int tokbase = (int)blkTok + w * 32;

        // scatter the 32 winning 1.0s + indices (lane t owns token t)
        if (lane < 32) {
            int fi = idxs[w * 32 + lane];
            oneh[(size_t)(tokbase + lane) * K + fi] = 1.0f;
            idxout[tokbase + lane] = (float)fi;
        }

        // qout: exact f32 codebook row; STE x + (q - x) (same expr as reference)
        #pragma unroll 1
        for (int t = 0; t < 32; ++t) {
            int fi = idxs[w * 32 + t];            // uniform per iteration
            const size_t tok = (size_t)tokbase + t;
            float q  = etf[(size_t)fi * D + lane];
            float xv = X[tok * D + lane];
            __builtin_nontemporal_store(xv + (q - xv), qout + tok * D + lane);
        }
    }
}

// ---- fallback (R1, proven) if workspace too small ----
__global__ __launch_bounds__(256, 2) void vq_fallback_kernel(
    const float* __restrict__ X, const float* __restrict__ E,
    float* __restrict__ qout, float* __restrict__ oneh, float* __restrict__ idxout)
{
    __shared__ float e2s[K];
    __shared__ int   idxs[256];
    const int tid = threadIdx.x;
    const int tok = blockIdx.x * 256 + tid;
    for (int k = tid; k < K; k += 256) {
        float s = 0.f;
        #pragma unroll
        for (int d = 0; d < D; ++d) { float v = E[d * K + k]; s = fmaf(v, v, s); }
        e2s[k] = s;
    }
    __syncthreads();
    float x[D];
    {
        const float* xp = X + (size_t)tok * D;
        #pragma unroll
        for (int j = 0; j < D / 4; ++j) {
            float4 v = *reinterpret_cast<const float4*>(xp + 4 * j);
            x[4*j+0]=v.x; x[4*j+1]=v.y; x[4*j+2]=v.z; x[4*j+3]=v.w;
        }
    }
    float best = 3.4e38f; int bidx = 0;
    for (int t0 = 0; t0 < K; t0 += 16) {
        float acc[16];
        #pragma unroll
        for (int j = 0; j < 16; ++j) acc[j] = 0.f;
        #pragma unroll
        for (int d = 0; d < D; ++d) {
            const float* ep = E + d * K + t0;
            #pragma unroll
            for (int j = 0; j < 16; ++j) acc[j] = fmaf(x[d], ep[j], acc[j]);
        }
        #pragma unroll
        for (int j = 0; j < 16; ++j) {
            float dist = fmaf(-2.f, acc[j], e2s[t0 + j]);
            if (dist < best) { best = dist; bidx = t0 + j; }
        }
    }
    idxs[tid] = bidx;
    {
        float q[D];
        const float* ec = E + bidx;
        #pragma unroll
        for (int d = 0; d < D; ++d) q[d] = ec[d * K];
        float* qp = qout + (size_t)tok * D;
        #pragma unroll
        for (int j = 0; j < D / 4; ++j) {
            float4 v;
            v.x = x[4*j+0] + (q[4*j+0] - x[4*j+0]);
            v.y = x[4*j+1] + (q[4*j+1] - x[4*j+1]);
            v.z = x[4*j+2] + (q[4*j+2] - x[4*j+2]);
            v.w = x[4*j+3] + (q[4*j+3] - x[4*j+3]);
            *reinterpret_cast<float4*>(qp + 4 * j) = v;
        }
    }
    idxout[tok] = (float)bidx;
    __syncthreads();
    {
        float4* base = reinterpret_cast<float4*>(oneh + (size_t)blockIdx.x * 256 * K);
        for (int i = tid; i < 256 * K / 4; i += 256) {
            int row = i >> 8, c4 = (i & 255) * 4, id = idxs[row];
            float4 v;
            v.x = (id == c4 + 0) ? 1.f : 0.f;
            v.y = (id == c4 + 1) ? 1.f : 0.f;
            v.z = (id == c4 + 2) ? 1.f : 0.f;
            v.w = (id == c4 + 3) ? 1.f : 0.f;
            base[i] = v;
        }
    }
}

extern "C" void kernel_launch(void* const* d_in, const int* in_sizes, int n_in,
                              void* d_out, int out_size, void* d_ws, size_t ws_size,
                              hipStream_t stream) {
    const float* X = (const float*)d_in[0];
    const float* E = (const float*)d_in[1];
    float* qout   = (float*)d_out;
    float* oneh   = qout + Q_ELEMS;
    float* idxout = oneh + OH_ELEMS;

    if (ws_size >= (size_t)WS_NEED) {
        float* ws = (float*)d_ws;
        prep_kernel<<<K / 256, 256, 0, stream>>>(E, ws);
        vq_fused_kernel<<<NTOK / 128, 512, 0, stream>>>(X, E, ws, qout, oneh, idxout);
    } else {
        vq_fallback_kernel<<<NTOK / 256, 256, 0, stream>>>(X, E, qout, oneh, idxout);
    }
}

// Round 18
// 223.099 us; speedup vs baseline: 1.1294x; 1.1294x over previous
//
#include <hip/hip_runtime.h>

#define D 64
#define K 1024
#define NTOK (32 * 4096)        // 131072 tokens
#define Q_ELEMS ((size_t)NTOK * D)
#define OH_ELEMS ((size_t)NTOK * K)

typedef short bf16x8 __attribute__((ext_vector_type(8)));
typedef float f32x4 __attribute__((ext_vector_type(4)));

// ws layout (bytes): e2[1024] f32 | etf[K][D] f32 | ethF frags | etlF frags
#define WS_ETF_OFF 4096                          // 256 KB exact transposed E
#define WS_ETH_OFF (4096 + 262144)               // 128 KB bf16-hi fragments
#define WS_ETL_OFF (4096 + 262144 + 131072)      // 128 KB bf16-lo fragments
#define WS_NEED    (4096 + 262144 + 131072 + 131072)

__device__ __forceinline__ unsigned short f2bf(float f) {   // RNE f32->bf16
    unsigned u = __float_as_uint(f);
    unsigned r = u + 0x7FFFu + ((u >> 16) & 1u);
    return (unsigned short)(r >> 16);
}
__device__ __forceinline__ float bf2f(unsigned short h) {
    return __uint_as_float(((unsigned)h) << 16);
}

// ---- prep: e2 (exact, d-ascending chain), etf, FRAGMENT-ORDERED bf16 tables ----
__global__ void prep_kernel(const float* __restrict__ E, float* __restrict__ ws) {
    int k = blockIdx.x * 256 + threadIdx.x;      // code
    float* e2 = ws;
    float* etf = (float*)((char*)ws + WS_ETF_OFF);
    unsigned short* ethF = (unsigned short*)((char*)ws + WS_ETH_OFF);
    unsigned short* etlF = (unsigned short*)((char*)ws + WS_ETL_OFF);

    const int tile = k >> 6, ct = (k >> 4) & 3, l15 = k & 15;
    float s = 0.f;
    #pragma unroll
    for (int d = 0; d < D; ++d) {
        float v = E[d * K + k];
        s = fmaf(v, v, s);
        etf[k * D + d] = v;
        unsigned short h = f2bf(v);
        unsigned short l = f2bf(v - bf2f(h));
        const int ks = d >> 5, g = (d >> 3) & 3, j = d & 7;
        const int slot = (((tile * 4 + ct) * 2 + ks) * 64 + g * 16 + l15) * 8 + j;
        ethF[slot] = h;
        etlF[slot] = l;
    }
    e2[k] = s;
}

// ---- exact rescore (bit-identical R1 chain, canonical ascending K); lane 0..63 ----
__device__ __attribute__((noinline)) int rescore_token(
    const float* __restrict__ X, const float* __restrict__ E,
    const float* __restrict__ e2g, int tok, int lane)
{
    const float* xr = X + (size_t)tok * D;
    float bestv = 3.4e38f; int besti = 0;
    #pragma unroll 1
    for (int sb = 0; sb < 2; ++sb) {
        const int k0 = lane * 16 + sb * 8;
        float dot[8] = {0.f,0.f,0.f,0.f,0.f,0.f,0.f,0.f};
        #pragma unroll 1
        for (int db = 0; db < 4; ++db) {
            float4 xc0 = *reinterpret_cast<const float4*>(xr + db * 16 + 0);
            float4 xc1 = *reinterpret_cast<const float4*>(xr + db * 16 + 4);
            float4 xc2 = *reinterpret_cast<const float4*>(xr + db * 16 + 8);
            float4 xc3 = *reinterpret_cast<const float4*>(xr + db * 16 + 12);
            float xs[16] = {xc0.x,xc0.y,xc0.z,xc0.w, xc1.x,xc1.y,xc1.z,xc1.w,
                            xc2.x,xc2.y,xc2.z,xc2.w, xc3.x,xc3.y,xc3.z,xc3.w};
            #pragma unroll
            for (int dd = 0; dd < 16; ++dd) {           // d ascending
                const int d = db * 16 + dd;
                float4 e0 = *reinterpret_cast<const float4*>(E + (size_t)d * K + k0);
                float4 e1 = *reinterpret_cast<const float4*>(E + (size_t)d * K + k0 + 4);
                dot[0] = fmaf(xs[dd], e0.x, dot[0]); dot[1] = fmaf(xs[dd], e0.y, dot[1]);
                dot[2] = fmaf(xs[dd], e0.z, dot[2]); dot[3] = fmaf(xs[dd], e0.w, dot[3]);
                dot[4] = fmaf(xs[dd], e1.x, dot[4]); dot[5] = fmaf(xs[dd], e1.y, dot[5]);
                dot[6] = fmaf(xs[dd], e1.z, dot[6]); dot[7] = fmaf(xs[dd], e1.w, dot[7]);
            }
        }
        float4 ez0 = *reinterpret_cast<const float4*>(e2g + k0);
        float4 ez1 = *reinterpret_cast<const float4*>(e2g + k0 + 4);
        float ezs[8] = {ez0.x,ez0.y,ez0.z,ez0.w, ez1.x,ez1.y,ez1.z,ez1.w};
        #pragma unroll
        for (int j = 0; j < 8; ++j) {
            float dist = fmaf(-2.f, dot[j], ezs[j]);
            if (dist < bestv) { bestv = dist; besti = k0 + j; }
        }
    }
    #pragma unroll
    for (int mm = 1; mm <= 32; mm <<= 1) {
        float ob = __shfl_xor(bestv, mm, 64);
        int   oi = __shfl_xor(besti, mm, 64);
        bool take = (ob < bestv) || (ob == bestv && oi < besti);
        bestv = take ? ob : bestv;
        besti = take ? oi : besti;
    }
    return besti;
}

// ---- main: R16 structure + block-parity phase stagger.
//      even blocks: compute -> fused full-row write (R16 verbatim).
//      odd blocks:  zero-stream first -> compute -> scatter 1s + qout + idx.
__global__ __launch_bounds__(256, 3) void vq_mfma_kernel(
    const float* __restrict__ X,
    const float* __restrict__ E,
    const float* __restrict__ ws_f,
    float* __restrict__ qout,
    float* __restrict__ oneh,
    float* __restrict__ idxout)
{
    // [buf][table][slot(ct*2+ks)][1KB: 64 lanes x 16B]  = 32 KB
    __shared__ __align__(16) unsigned short btile[2][2][8][512];

    const int lane   = threadIdx.x & 63;
    const int wv     = threadIdx.x >> 6;          // wave 0..3
    const int lane15 = lane & 15;
    const int g      = lane >> 4;                 // 0..3
    const int tokbase = blockIdx.x * 128 + wv * 32;
    const bool odd = (blockIdx.x & 1) != 0;

    const float* e2g = ws_f;
    const float* etf = (const float*)((const char*)ws_f + WS_ETF_OFF);
    const char* ethB = (const char*)ws_f + WS_ETH_OFF;
    const char* etlB = (const char*)ws_f + WS_ETL_OFF;

    // A fragments for 2 M-tiles (mapping proven R6-R17)
    bf16x8 ah[2][2], al[2][2];                    // [mtile][ks]
    #pragma unroll
    for (int mt = 0; mt < 2; ++mt) {
        const float* xr = X + (size_t)(tokbase + mt * 16 + lane15) * D + g * 8;
        #pragma unroll
        for (int ks = 0; ks < 2; ++ks) {
            float4 v0 = *reinterpret_cast<const float4*>(xr + ks * 32);
            float4 v1 = *reinterpret_cast<const float4*>(xr + ks * 32 + 4);
            float xv[8] = {v0.x,v0.y,v0.z,v0.w, v1.x,v1.y,v1.z,v1.w};
            #pragma unroll
            for (int j = 0; j < 8; ++j) {
                unsigned short h = f2bf(xv[j]);
                ah[mt][ks][j] = (short)h;
                al[mt][ks][j] = (short)f2bf(xv[j] - bf2f(h));
            }
        }
    }

    // odd blocks: stream one-hot ZEROS up front (independent of compute);
    // each wave zeroes its OWN 32 rows -> own-wave vmcnt ordering suffices.
    if (odd) {
        f32x4* ohz = reinterpret_cast<f32x4*>(oneh + (size_t)tokbase * K);
        const f32x4 zv = {0.f, 0.f, 0.f, 0.f};
        #pragma unroll 4
        for (int i = 0; i < 128; ++i)             // 32 rows x 4KB = 128 x 1KB chunks
            __builtin_nontemporal_store(zv, ohz + i * 64 + lane);
    }

    float bb[2][4] = {{3.4e38f,3.4e38f,3.4e38f,3.4e38f},{3.4e38f,3.4e38f,3.4e38f,3.4e38f}};
    float b2[2][4] = {{3.4e38f,3.4e38f,3.4e38f,3.4e38f},{3.4e38f,3.4e38f,3.4e38f,3.4e38f}};
    int   bi[2][4] = {{0,0,0,0},{0,0,0,0}};

    #define GLOAD_TILE(T, B)                                                          \
        do {                                                                          \
            _Pragma("unroll")                                                         \
            for (int cc = 0; cc < 4; ++cc) {                                          \
                const int c = wv * 4 + cc;                                            \
                const char* src = ((c < 8) ? ethB : etlB)                             \
                                  + (size_t)(T) * 8192 + (size_t)(c & 7) * 1024       \
                                  + (size_t)lane * 16;                                \
                __builtin_amdgcn_global_load_lds(                                     \
                    (const __attribute__((address_space(1))) void*)src,               \
                    (__attribute__((address_space(3))) void*)&btile[B][c >> 3][c & 7][0], \
                    16, 0, 0);                                                        \
            }                                                                         \
        } while (0)

    GLOAD_TILE(0, 0);

    #pragma unroll 1
    for (int tile = 0; tile < 16; ++tile) {
        const int buf = tile & 1;
        __syncthreads();                        // drains gload (and odd's zeros once)
        if (tile < 15) GLOAD_TILE(tile + 1, buf ^ 1);

        #pragma unroll
        for (int ct = 0; ct < 4; ++ct) {
            const int code = tile * 64 + ct * 16 + lane15;
            f32x4 acc0 = {0.f,0.f,0.f,0.f};
            f32x4 acc1 = {0.f,0.f,0.f,0.f};
            #pragma unroll
            for (int ks = 0; ks < 2; ++ks) {
                const int slot = ct * 2 + ks;
                bf16x8 bh = reinterpret_cast<const bf16x8*>(&btile[buf][0][slot][0])[lane];
                bf16x8 bl = reinterpret_cast<const bf16x8*>(&btile[buf][1][slot][0])[lane];
                acc0 = __builtin_amdgcn_mfma_f32_16x16x32_bf16(ah[0][ks], bh, acc0, 0, 0, 0);
                acc0 = __builtin_amdgcn_mfma_f32_16x16x32_bf16(ah[0][ks], bl, acc0, 0, 0, 0);
                acc0 = __builtin_amdgcn_mfma_f32_16x16x32_bf16(al[0][ks], bh, acc0, 0, 0, 0);
                acc1 = __builtin_amdgcn_mfma_f32_16x16x32_bf16(ah[1][ks], bh, acc1, 0, 0, 0);
                acc1 = __builtin_amdgcn_mfma_f32_16x16x32_bf16(ah[1][ks], bl, acc1, 0, 0, 0);
                acc1 = __builtin_amdgcn_mfma_f32_16x16x32_bf16(al[1][ks], bh, acc1, 0, 0, 0);
            }
            const float e2v = e2g[code];
            #pragma unroll
            for (int r = 0; r < 4; ++r) {   // C/D: col=lane15=code, row=g*4+r=token
                float d0 = fmaf(-2.f, acc0[r], e2v);
                b2[0][r] = fminf(b2[0][r], fmaxf(bb[0][r], d0));
                if (d0 < bb[0][r]) { bb[0][r] = d0; bi[0][r] = code; }
                float d1 = fmaf(-2.f, acc1[r], e2v);
                b2[1][r] = fminf(b2[1][r], fmaxf(bb[1][r], d1));
                if (d1 < bb[1][r]) { bb[1][r] = d1; bi[1][r] = code; }
            }
        }
    }

    // reduce best/best2 over the 16 lanes sharing each token row
    #pragma unroll
    for (int m = 1; m <= 8; m <<= 1) {
        #pragma unroll
        for (int mt = 0; mt < 2; ++mt) {
            #pragma unroll
            for (int r = 0; r < 4; ++r) {
                float ob = __shfl_xor(bb[mt][r], m, 64);
                float o2 = __shfl_xor(b2[mt][r], m, 64);
                int   oi = __shfl_xor(bi[mt][r], m, 64);
                float nb2 = fminf(fminf(b2[mt][r], o2), fmaxf(bb[mt][r], ob));
                bool take = (ob < bb[mt][r]) || (ob == bb[mt][r] && oi < bi[mt][r]);
                bb[mt][r] = take ? ob : bb[mt][r];
                bi[mt][r] = take ? oi : bi[mt][r];
                b2[mt][r] = nb2;
            }
        }
    }

    // margin-guarded exact rescore (tau = 0.125, proven R6-R17)
    #pragma unroll
    for (int mt = 0; mt < 2; ++mt) {
        #pragma unroll
        for (int r = 0; r < 4; ++r) {
            bool flag = (b2[mt][r] - bb[mt][r]) < 0.125f;
            unsigned long long m = __ballot(flag);
            if (m) {
                #pragma unroll
                for (int gg = 0; gg < 4; ++gg) {
                    if ((m >> (gg * 16)) & 1ULL) {
                        int ei = rescore_token(X, E, e2g, tokbase + mt * 16 + gg * 4 + r, lane);
                        if (g == gg) bi[mt][r] = ei;
                    }
                }
            }
        }
    }

    if (!odd) {
        // ---- EVEN epilogue (R16 verbatim): fused full one-hot rows + qout + idx ----
        #pragma unroll
        for (int t = 0; t < 32; ++t) {
            const int t16 = t & 15;
            const int fi = __shfl(bi[t >> 4][t16 & 3], (t16 >> 2) * 16, 64);
            const size_t tok = (size_t)tokbase + t;

            float q  = etf[(size_t)fi * D + lane];
            float xv = X[tok * D + lane];
            __builtin_nontemporal_store(xv + (q - xv), qout + tok * D + lane);

            if (lane == t) idxout[tok] = (float)fi;

            f32x4* row = reinterpret_cast<f32x4*>(oneh + tok * (size_t)K);
            #pragma unroll
            for (int c = 0; c < 4; ++c) {
                const int c4 = (c * 64 + lane) * 4;
                f32x4 v;
                v[0] = (fi == c4 + 0) ? 1.f : 0.f;
                v[1] = (fi == c4 + 1) ? 1.f : 0.f;
                v[2] = (fi == c4 + 2) ? 1.f : 0.f;
                v[3] = (fi == c4 + 3) ? 1.f : 0.f;
                __builtin_nontemporal_store(v, row + c * 64 + lane);
            }
        }
    } else {
        // ---- ODD epilogue: qout + idx, then scatter 1s over the pre-zeroed rows ----
        int fi_lane = 0;
        #pragma unroll
        for (int t = 0; t < 32; ++t) {
            const int t16 = t & 15;
            const int fi = __shfl(bi[t >> 4][t16 & 3], (t16 >> 2) * 16, 64);
            if ((lane & 31) == t) fi_lane = fi;

            const size_t tok = (size_t)tokbase + t;
            float q  = etf[(size_t)fi * D + lane];
            float xv = X[tok * D + lane];
            __builtin_nontemporal_store(xv + (q - xv), qout + tok * D + lane);
        }
        // drain own zero stores (FIFO vmcnt long since empty of them, but explicit)
        __builtin_amdgcn_s_waitcnt(0);
        if (lane < 32) {
            oneh[(size_t)(tokbase + lane) * K + fi_lane] = 1.0f;
            idxout[tokbase + lane] = (float)fi_lane;
        }
    }
}

// ---- fallback (R1, proven) if workspace too small ----
__global__ __launch_bounds__(256, 2) void vq_fallback_kernel(
    const float* __restrict__ X, const float* __restrict__ E,
    float* __restrict__ qout, float* __restrict__ oneh, float* __restrict__ idxout)
{
    __shared__ float e2s[K];
    __shared__ int   idxs[256];
    const int tid = threadIdx.x;
    const int tok = blockIdx.x * 256 + tid;
    for (int k = tid; k < K; k += 256) {
        float s = 0.f;
        #pragma unroll
        for (int d = 0; d < D; ++d) { float v = E[d * K + k]; s = fmaf(v, v, s); }
        e2s[k] = s;
    }
    __syncthreads();
    float x[D];
    {
        const float* xp = X + (size_t)tok * D;
        #pragma unroll
        for (int j = 0; j < D / 4; ++j) {
            float4 v = *reinterpret_cast<const float4*>(xp + 4 * j);
            x[4*j+0]=v.x; x[4*j+1]=v.y; x[4*j+2]=v.z; x[4*j+3]=v.w;
        }
    }
    float best = 3.4e38f; int bidx = 0;
    for (int t0 = 0; t0 < K; t0 += 16) {
        float acc[16];
        #pragma unroll
        for (int j = 0; j < 16; ++j) acc[j] = 0.f;
        #pragma unroll
        for (int d = 0; d < D; ++d) {
            const float* ep = E + d * K + t0;
            #pragma unroll
            for (int j = 0; j < 16; ++j) acc[j] = fmaf(x[d], ep[j], acc[j]);
        }
        #pragma unroll
        for (int j = 0; j < 16; ++j) {
            float dist = fmaf(-2.f, acc[j], e2s[t0 + j]);
            if (dist < best) { best = dist; bidx = t0 + j; }
        }
    }
    idxs[tid] = bidx;
    {
        float q[D];
        const float* ec = E + bidx;
        #pragma unroll
        for (int d = 0; d < D; ++d) q[d] = ec[d * K];
        float* qp = qout + (size_t)tok * D;
        #pragma unroll
        for (int j = 0; j < D / 4; ++j) {
            float4 v;
            v.x = x[4*j+0] + (q[4*j+0] - x[4*j+0]);
            v.y = x[4*j+1] + (q[4*j+1] - x[4*j+1]);
            v.z = x[4*j+2] + (q[4*j+2] - x[4*j+2]);
            v.w = x[4*j+3] + (q[4*j+3] - x[4*j+3]);
            *reinterpret_cast<float4*>(qp + 4 * j) = v;
        }
    }
    idxout[tok] = (float)bidx;
    __syncthreads();
    {
        float4* base = reinterpret_cast<float4*>(oneh + (size_t)blockIdx.x * 256 * K);
        for (int i = tid; i < 256 * K / 4; i += 256) {
            int row = i >> 8, c4 = (i & 255) * 4, id = idxs[row];
            float4 v;
            v.x = (id == c4 + 0) ? 1.f : 0.f;
            v.y = (id == c4 + 1) ? 1.f : 0.f;
            v.z = (id == c4 + 2) ? 1.f : 0.f;
            v.w = (id == c4 + 3) ? 1.f : 0.f;
            base[i] = v;
        }
    }
}

extern "C" void kernel_launch(void* const* d_in, const int* in_sizes, int n_in,
                              void* d_out, int out_size, void* d_ws, size_t ws_size,
                              hipStream_t stream) {
    const float* X = (const float*)d_in[0];
    const float* E = (const float*)d_in[1];
    float* qout   = (float*)d_out;
    float* oneh   = qout + Q_ELEMS;
    float* idxout = oneh + OH_ELEMS;

    if (ws_size >= (size_t)WS_NEED) {
        float* ws = (float*)d_ws;
        prep_kernel<<<K / 256, 256, 0, stream>>>(E, ws);
        vq_mfma_kernel<<<NTOK / 128, 256, 0, stream>>>(X, E, ws, qout, oneh, idxout);
    } else {
        vq_fallback_kernel<<<NTOK / 256, 256, 0, stream>>>(X, E, qout, oneh, idxout);
    }
}

// Round 19
// 214.385 us; speedup vs baseline: 1.1753x; 1.0406x over previous
//
#include <hip/hip_runtime.h>

#define D 64
#define K 1024
#define NTOK (32 * 4096)        // 131072 tokens
#define Q_ELEMS ((size_t)NTOK * D)
#define OH_ELEMS ((size_t)NTOK * K)

typedef short bf16x8 __attribute__((ext_vector_type(8)));
typedef float f32x4 __attribute__((ext_vector_type(4)));

// ws layout (bytes): e2[1024] f32 | etf[K][D] f32 | ethF frags | etlF frags
#define WS_ETF_OFF 4096                          // 256 KB exact transposed E
#define WS_ETH_OFF (4096 + 262144)               // 128 KB bf16-hi fragments
#define WS_ETL_OFF (4096 + 262144 + 131072)      // 128 KB bf16-lo fragments
#define WS_NEED    (4096 + 262144 + 131072 + 131072)

__device__ __forceinline__ unsigned short f2bf(float f) {   // RNE f32->bf16
    unsigned u = __float_as_uint(f);
    unsigned r = u + 0x7FFFu + ((u >> 16) & 1u);
    return (unsigned short)(r >> 16);
}
__device__ __forceinline__ float bf2f(unsigned short h) {
    return __uint_as_float(((unsigned)h) << 16);
}

// ---- prep: e2 (exact, d-ascending chain), etf, FRAGMENT-ORDERED bf16 tables ----
__global__ void prep_kernel(const float* __restrict__ E, float* __restrict__ ws) {
    int k = blockIdx.x * 256 + threadIdx.x;      // code
    float* e2 = ws;
    float* etf = (float*)((char*)ws + WS_ETF_OFF);
    unsigned short* ethF = (unsigned short*)((char*)ws + WS_ETH_OFF);
    unsigned short* etlF = (unsigned short*)((char*)ws + WS_ETL_OFF);

    const int tile = k >> 6, ct = (k >> 4) & 3, l15 = k & 15;
    float s = 0.f;
    #pragma unroll
    for (int d = 0; d < D; ++d) {
        float v = E[d * K + k];
        s = fmaf(v, v, s);
        etf[k * D + d] = v;
        unsigned short h = f2bf(v);
        unsigned short l = f2bf(v - bf2f(h));
        const int ks = d >> 5, g = (d >> 3) & 3, j = d & 7;
        const int slot = (((tile * 4 + ct) * 2 + ks) * 64 + g * 16 + l15) * 8 + j;
        ethF[slot] = h;
        etlF[slot] = l;
    }
    e2[k] = s;
}

// ---- exact rescore (bit-identical R1 chain, canonical ascending K); lane 0..63 ----
__device__ __attribute__((noinline)) int rescore_token(
    const float* __restrict__ X, const float* __restrict__ E,
    const float* __restrict__ e2g, int tok, int lane)
{
    const float* xr = X + (size_t)tok * D;
    float bestv = 3.4e38f; int besti = 0;
    #pragma unroll 1
    for (int sb = 0; sb < 2; ++sb) {
        const int k0 = lane * 16 + sb * 8;
        float dot[8] = {0.f,0.f,0.f,0.f,0.f,0.f,0.f,0.f};
        #pragma unroll 1
        for (int db = 0; db < 4; ++db) {
            float4 xc0 = *reinterpret_cast<const float4*>(xr + db * 16 + 0);
            float4 xc1 = *reinterpret_cast<const float4*>(xr + db * 16 + 4);
            float4 xc2 = *reinterpret_cast<const float4*>(xr + db * 16 + 8);
            float4 xc3 = *reinterpret_cast<const float4*>(xr + db * 16 + 12);
            float xs[16] = {xc0.x,xc0.y,xc0.z,xc0.w, xc1.x,xc1.y,xc1.z,xc1.w,
                            xc2.x,xc2.y,xc2.z,xc2.w, xc3.x,xc3.y,xc3.z,xc3.w};
            #pragma unroll
            for (int dd = 0; dd < 16; ++dd) {           // d ascending
                const int d = db * 16 + dd;
                float4 e0 = *reinterpret_cast<const float4*>(E + (size_t)d * K + k0);
                float4 e1 = *reinterpret_cast<const float4*>(E + (size_t)d * K + k0 + 4);
                dot[0] = fmaf(xs[dd], e0.x, dot[0]); dot[1] = fmaf(xs[dd], e0.y, dot[1]);
                dot[2] = fmaf(xs[dd], e0.z, dot[2]); dot[3] = fmaf(xs[dd], e0.w, dot[3]);
                dot[4] = fmaf(xs[dd], e1.x, dot[4]); dot[5] = fmaf(xs[dd], e1.y, dot[5]);
                dot[6] = fmaf(xs[dd], e1.z, dot[6]); dot[7] = fmaf(xs[dd], e1.w, dot[7]);
            }
        }
        float4 ez0 = *reinterpret_cast<const float4*>(e2g + k0);
        float4 ez1 = *reinterpret_cast<const float4*>(e2g + k0 + 4);
        float ezs[8] = {ez0.x,ez0.y,ez0.z,ez0.w, ez1.x,ez1.y,ez1.z,ez1.w};
        #pragma unroll
        for (int j = 0; j < 8; ++j) {
            float dist = fmaf(-2.f, dot[j], ezs[j]);
            if (dist < bestv) { bestv = dist; besti = k0 + j; }
        }
    }
    #pragma unroll
    for (int mm = 1; mm <= 32; mm <<= 1) {
        float ob = __shfl_xor(bestv, mm, 64);
        int   oi = __shfl_xor(besti, mm, 64);
        bool take = (ob < bestv) || (ob == bestv && oi < besti);
        bestv = take ? ob : bestv;
        besti = take ? oi : besti;
    }
    return besti;
}

// ---- main: R16 structure, but 3 INDEPENDENT accumulators per M-tile
//      (6 independent MFMA streams per ct-iter -> no dependent chains);
//      launch_bounds back to (256,2) = 128-VGPR cap (no spill) ----
__global__ __launch_bounds__(256, 2) void vq_mfma_kernel(
    const float* __restrict__ X,
    const float* __restrict__ E,
    const float* __restrict__ ws_f,
    float* __restrict__ qout,
    float* __restrict__ oneh,
    float* __restrict__ idxout)
{
    // [buf][table][slot(ct*2+ks)][1KB: 64 lanes x 16B]  = 32 KB
    __shared__ __align__(16) unsigned short btile[2][2][8][512];

    const int lane   = threadIdx.x & 63;
    const int wv     = threadIdx.x >> 6;          // wave 0..3
    const int lane15 = lane & 15;
    const int g      = lane >> 4;                 // 0..3
    const int tokbase = blockIdx.x * 128 + wv * 32;

    const float* e2g = ws_f;
    const float* etf = (const float*)((const char*)ws_f + WS_ETF_OFF);
    const char* ethB = (const char*)ws_f + WS_ETH_OFF;
    const char* etlB = (const char*)ws_f + WS_ETL_OFF;

    // A fragments for 2 M-tiles (mapping proven R6-R18)
    bf16x8 ah[2][2], al[2][2];                    // [mtile][ks]
    #pragma unroll
    for (int mt = 0; mt < 2; ++mt) {
        const float* xr = X + (size_t)(tokbase + mt * 16 + lane15) * D + g * 8;
        #pragma unroll
        for (int ks = 0; ks < 2; ++ks) {
            float4 v0 = *reinterpret_cast<const float4*>(xr + ks * 32);
            float4 v1 = *reinterpret_cast<const float4*>(xr + ks * 32 + 4);
            float xv[8] = {v0.x,v0.y,v0.z,v0.w, v1.x,v1.y,v1.z,v1.w};
            #pragma unroll
            for (int j = 0; j < 8; ++j) {
                unsigned short h = f2bf(xv[j]);
                ah[mt][ks][j] = (short)h;
                al[mt][ks][j] = (short)f2bf(xv[j] - bf2f(h));
            }
        }
    }

    float bb[2][4] = {{3.4e38f,3.4e38f,3.4e38f,3.4e38f},{3.4e38f,3.4e38f,3.4e38f,3.4e38f}};
    float b2[2][4] = {{3.4e38f,3.4e38f,3.4e38f,3.4e38f},{3.4e38f,3.4e38f,3.4e38f,3.4e38f}};
    int   bi[2][4] = {{0,0,0,0},{0,0,0,0}};

    #define GLOAD_TILE(T, B)                                                          \
        do {                                                                          \
            _Pragma("unroll")                                                         \
            for (int cc = 0; cc < 4; ++cc) {                                          \
                const int c = wv * 4 + cc;                                            \
                const char* src = ((c < 8) ? ethB : etlB)                             \
                                  + (size_t)(T) * 8192 + (size_t)(c & 7) * 1024       \
                                  + (size_t)lane * 16;                                \
                __builtin_amdgcn_global_load_lds(                                     \
                    (const __attribute__((address_space(1))) void*)src,               \
                    (__attribute__((address_space(3))) void*)&btile[B][c >> 3][c & 7][0], \
                    16, 0, 0);                                                        \
            }                                                                         \
        } while (0)

    GLOAD_TILE(0, 0);

    #pragma unroll 1
    for (int tile = 0; tile < 16; ++tile) {
        const int buf = tile & 1;
        __syncthreads();                        // vmcnt(0)-drain completes buf's loads
        if (tile < 15) GLOAD_TILE(tile + 1, buf ^ 1);

        #pragma unroll
        for (int ct = 0; ct < 4; ++ct) {
            const int code = tile * 64 + ct * 16 + lane15;
            // 6 INDEPENDENT accumulators: no MFMA->MFMA dependency within ct
            f32x4 a0hh = {0.f,0.f,0.f,0.f}, a0hl = {0.f,0.f,0.f,0.f}, a0lh = {0.f,0.f,0.f,0.f};
            f32x4 a1hh = {0.f,0.f,0.f,0.f}, a1hl = {0.f,0.f,0.f,0.f}, a1lh = {0.f,0.f,0.f,0.f};
            #pragma unroll
            for (int ks = 0; ks < 2; ++ks) {
                const int slot = ct * 2 + ks;
                bf16x8 bh = reinterpret_cast<const bf16x8*>(&btile[buf][0][slot][0])[lane];
                bf16x8 bl = reinterpret_cast<const bf16x8*>(&btile[buf][1][slot][0])[lane];
                a0hh = __builtin_amdgcn_mfma_f32_16x16x32_bf16(ah[0][ks], bh, a0hh, 0, 0, 0);
                a0hl = __builtin_amdgcn_mfma_f32_16x16x32_bf16(ah[0][ks], bl, a0hl, 0, 0, 0);
                a0lh = __builtin_amdgcn_mfma_f32_16x16x32_bf16(al[0][ks], bh, a0lh, 0, 0, 0);
                a1hh = __builtin_amdgcn_mfma_f32_16x16x32_bf16(ah[1][ks], bh, a1hh, 0, 0, 0);
                a1hl = __builtin_amdgcn_mfma_f32_16x16x32_bf16(ah[1][ks], bl, a1hl, 0, 0, 0);
                a1lh = __builtin_amdgcn_mfma_f32_16x16x32_bf16(al[1][ks], bh, a1lh, 0, 0, 0);
            }
            const float e2v = e2g[code];
            #pragma unroll
            for (int r = 0; r < 4; ++r) {   // C/D: col=lane15=code, row=g*4+r=token
                float s0 = (a0hh[r] + a0hl[r]) + a0lh[r];
                float d0 = fmaf(-2.f, s0, e2v);
                b2[0][r] = fminf(b2[0][r], fmaxf(bb[0][r], d0));
                if (d0 < bb[0][r]) { bb[0][r] = d0; bi[0][r] = code; }
                float s1 = (a1hh[r] + a1hl[r]) + a1lh[r];
                float d1 = fmaf(-2.f, s1, e2v);
                b2[1][r] = fminf(b2[1][r], fmaxf(bb[1][r], d1));
                if (d1 < bb[1][r]) { bb[1][r] = d1; bi[1][r] = code; }
            }
        }
    }

    // reduce best/best2 over the 16 lanes sharing each token row
    #pragma unroll
    for (int m = 1; m <= 8; m <<= 1) {
        #pragma unroll
        for (int mt = 0; mt < 2; ++mt) {
            #pragma unroll
            for (int r = 0; r < 4; ++r) {
                float ob = __shfl_xor(bb[mt][r], m, 64);
                float o2 = __shfl_xor(b2[mt][r], m, 64);
                int   oi = __shfl_xor(bi[mt][r], m, 64);
                float nb2 = fminf(fminf(b2[mt][r], o2), fmaxf(bb[mt][r], ob));
                bool take = (ob < bb[mt][r]) || (ob == bb[mt][r] && oi < bi[mt][r]);
                bb[mt][r] = take ? ob : bb[mt][r];
                bi[mt][r] = take ? oi : bi[mt][r];
                b2[mt][r] = nb2;
            }
        }
    }

    // margin-guarded exact rescore (tau = 0.125 >> approx-path error ~0.01;
    // absorbs the accumulator-ordering change, proven mechanism R6-R18)
    #pragma unroll
    for (int mt = 0; mt < 2; ++mt) {
        #pragma unroll
        for (int r = 0; r < 4; ++r) {
            bool flag = (b2[mt][r] - bb[mt][r]) < 0.125f;
            unsigned long long m = __ballot(flag);
            if (m) {
                #pragma unroll
                for (int gg = 0; gg < 4; ++gg) {
                    if ((m >> (gg * 16)) & 1ULL) {
                        int ei = rescore_token(X, E, e2g, tokbase + mt * 16 + gg * 4 + r, lane);
                        if (g == gg) bi[mt][r] = ei;
                    }
                }
            }
        }
    }

    // ---- epilogue (R10/R16 proven verbatim): qout + idx + one-hot, nt stores ----
    #pragma unroll
    for (int t = 0; t < 32; ++t) {
        const int t16 = t & 15;
        const int fi = __shfl(bi[t >> 4][t16 & 3], (t16 >> 2) * 16, 64);
        const size_t tok = (size_t)tokbase + t;

        float q  = etf[(size_t)fi * D + lane];
        float xv = X[tok * D + lane];
        __builtin_nontemporal_store(xv + (q - xv), qout + tok * D + lane);

        if (lane == t) idxout[tok] = (float)fi;

        f32x4* row = reinterpret_cast<f32x4*>(oneh + tok * (size_t)K);
        #pragma unroll
        for (int c = 0; c < 4; ++c) {
            const int c4 = (c * 64 + lane) * 4;
            f32x4 v;
            v[0] = (fi == c4 + 0) ? 1.f : 0.f;
            v[1] = (fi == c4 + 1) ? 1.f : 0.f;
            v[2] = (fi == c4 + 2) ? 1.f : 0.f;
            v[3] = (fi == c4 + 3) ? 1.f : 0.f;
            __builtin_nontemporal_store(v, row + c * 64 + lane);
        }
    }
}

// ---- fallback (R1, proven) if workspace too small ----
__global__ __launch_bounds__(256, 2) void vq_fallback_kernel(
    const float* __restrict__ X, const float* __restrict__ E,
    float* __restrict__ qout, float* __restrict__ oneh, float* __restrict__ idxout)
{
    __shared__ float e2s[K];
    __shared__ int   idxs[256];
    const int tid = threadIdx.x;
    const int tok = blockIdx.x * 256 + tid;
    for (int k = tid; k < K; k += 256) {
        float s = 0.f;
        #pragma unroll
        for (int d = 0; d < D; ++d) { float v = E[d * K + k]; s = fmaf(v, v, s); }
        e2s[k] = s;
    }
    __syncthreads();
    float x[D];
    {
        const float* xp = X + (size_t)tok * D;
        #pragma unroll
        for (int j = 0; j < D / 4; ++j) {
            float4 v = *reinterpret_cast<const float4*>(xp + 4 * j);
            x[4*j+0]=v.x; x[4*j+1]=v.y; x[4*j+2]=v.z; x[4*j+3]=v.w;
        }
    }
    float best = 3.4e38f; int bidx = 0;
    for (int t0 = 0; t0 < K; t0 += 16) {
        float acc[16];
        #pragma unroll
        for (int j = 0; j < 16; ++j) acc[j] = 0.f;
        #pragma unroll
        for (int d = 0; d < D; ++d) {
            const float* ep = E + d * K + t0;
            #pragma unroll
            for (int j = 0; j < 16; ++j) acc[j] = fmaf(x[d], ep[j], acc[j]);
        }
        #pragma unroll
        for (int j = 0; j < 16; ++j) {
            float dist = fmaf(-2.f, acc[j], e2s[t0 + j]);
            if (dist < best) { best = dist; bidx = t0 + j; }
        }
    }
    idxs[tid] = bidx;
    {
        float q[D];
        const float* ec = E + bidx;
        #pragma unroll
        for (int d = 0; d < D; ++d) q[d] = ec[d * K];
        float* qp = qout + (size_t)tok * D;
        #pragma unroll
        for (int j = 0; j < D / 4; ++j) {
            float4 v;
            v.x = x[4*j+0] + (q[4*j+0] - x[4*j+0]);
            v.y = x[4*j+1] + (q[4*j+1] - x[4*j+1]);
            v.z = x[4*j+2] + (q[4*j+2] - x[4*j+2]);
            v.w = x[4*j+3] + (q[4*j+3] - x[4*j+3]);
            *reinterpret_cast<float4*>(qp + 4 * j) = v;
        }
    }
    idxout[tok] = (float)bidx;
    __syncthreads();
    {
        float4* base = reinterpret_cast<float4*>(oneh + (size_t)blockIdx.x * 256 * K);
        for (int i = tid; i < 256 * K / 4; i += 256) {
            int row = i >> 8, c4 = (i & 255) * 4, id = idxs[row];
            float4 v;
            v.x = (id == c4 + 0) ? 1.f : 0.f;
            v.y = (id == c4 + 1) ? 1.f : 0.f;
            v.z = (id == c4 + 2) ? 1.f : 0.f;
            v.w = (id == c4 + 3) ? 1.f : 0.f;
            base[i] = v;
        }
    }
}

extern "C" void kernel_launch(void* const* d_in, const int* in_sizes, int n_in,
                              void* d_out, int out_size, void* d_ws, size_t ws_size,
                              hipStream_t stream) {
    const float* X = (const float*)d_in[0];
    const float* E = (const float*)d_in[1];
    float* qout   = (float*)d_out;
    float* oneh   = qout + Q_ELEMS;
    float* idxout = oneh + OH_ELEMS;

    if (ws_size >= (size_t)WS_NEED) {
        float* ws = (float*)d_ws;
        prep_kernel<<<K / 256, 256, 0, stream>>>(E, ws);
        vq_mfma_kernel<<<NTOK / 128, 256, 0, stream>>>(X, E, ws, qout, oneh, idxout);
    } else {
        vq_fallback_kernel<<<NTOK / 256, 256, 0, stream>>>(X, E, qout, oneh, idxout);
    }
}